// Round 2
// baseline (366.087 us; speedup 1.0000x reference)
//
#include <hip/hip_runtime.h>
#include <hip/hip_bf16.h>

// ---- types ----
typedef __attribute__((ext_vector_type(8))) short v8s;   // 8 x bf16 (MFMA A/B frag)
typedef __attribute__((ext_vector_type(4))) short v4s;   // 4 x bf16
typedef __attribute__((ext_vector_type(4))) float v4f;   // MFMA C/D frag

#define S_LEN 2048
#define NB 4
#define NH 16
#define LOG2E 1.4426950408889634f
#define C2MASK 1.4426950408889634e12f   // 1e12 * log2(e), fp32-collapses small addends

__device__ __forceinline__ short f2bf(float f) {
    __hip_bfloat16 h = __float2bfloat16(f);
    union { __hip_bfloat16 h; short s; } u; u.h = h; return u.s;
}

// st_16x32 swizzle for 128B-row LDS tiles (m201: verified conflict-killer for
// 16x16x32 MFMA fragment reads from [R][64-bf16] tiles)
__device__ __forceinline__ int swz(int b) { return b ^ (((b >> 9) & 1) << 5); }

__device__ __forceinline__ void async16(void* lds, const void* g) {
    __builtin_amdgcn_global_load_lds(
        (const __attribute__((address_space(1))) unsigned int*)g,
        (__attribute__((address_space(3))) unsigned int*)lds, 16, 0, 0);
}

#define MFMA16(a, b, c) __builtin_amdgcn_mfma_f32_16x16x32_bf16((a), (b), (c), 0, 0, 0)

// ---------------- convert fp32 -> bf16 (vectorized, G13) ----------------
__global__ __launch_bounds__(256) void convert_f32_bf16(const float* __restrict__ in,
                                                        short* __restrict__ out) {
    size_t i = ((size_t)blockIdx.x * 256 + threadIdx.x) * 8;
    float4 a = *(const float4*)(in + i);
    float4 b = *(const float4*)(in + i + 4);
    v8s o;
    o[0] = f2bf(a.x); o[1] = f2bf(a.y); o[2] = f2bf(a.z); o[3] = f2bf(a.w);
    o[4] = f2bf(b.x); o[5] = f2bf(b.y); o[6] = f2bf(b.z); o[7] = f2bf(b.w);
    *(v8s*)(out + i) = o;
}

// ---------------- W[K][N] fp32 -> WT[N][K] bf16 ----------------
__global__ __launch_bounds__(256) void transpose_w(const float* __restrict__ W,
                                                   short* __restrict__ WT) {
    __shared__ float tile[32][33];
    int k0 = blockIdx.x * 32, n0 = blockIdx.y * 32;
    int tx = threadIdx.x & 31, ty = threadIdx.x >> 5;  // ty 0..7
#pragma unroll
    for (int i = 0; i < 4; ++i)
        tile[ty + i * 8][tx] = W[(size_t)(k0 + ty + i * 8) * 1024 + n0 + tx];
    __syncthreads();
#pragma unroll
    for (int i = 0; i < 4; ++i)
        WT[(size_t)(n0 + ty + i * 8) * 1024 + k0 + tx] = f2bf(tile[tx][ty + i * 8]);
}

// ---------------- fused QKV projection GEMM (m97 structure) ----------------
// C[8192x1024] = X[8192x1024] @ W + b ; z selects Q/K/V. 128x128 tile, BK=64.
// Q: *0.125*log2e folded (exp2-domain softmax), -> [b,h,s,d]. K: -> [b,h,s,d].
// V: -> transposed [b,h,d,s].
__global__ __launch_bounds__(256)
void proj_gemm(const short* __restrict__ Xq, const short* __restrict__ Xk,
               const short* __restrict__ Xv,
               const short* __restrict__ WTq, const short* __restrict__ WTk,
               const short* __restrict__ WTv,
               const float* __restrict__ bq, const float* __restrict__ bk,
               const float* __restrict__ bv,
               short* __restrict__ QW, short* __restrict__ KW, short* __restrict__ VT) {
    __shared__ short As[128 * 64];
    __shared__ short Bs[128 * 64];
    const int tid = threadIdx.x;
    const int l = tid & 63, w = tid >> 6;
    const int g = l >> 4, ql = l & 15;
    const int m0 = blockIdx.x * 128, n0 = blockIdx.y * 128;
    const int z = blockIdx.z;
    const short* A  = (z == 0) ? Xq : (z == 1) ? Xk : Xv;
    const short* BT = (z == 0) ? WTq : (z == 1) ? WTk : WTv;
    const float* bias = (z == 0) ? bq : (z == 1) ? bk : bv;
    const int wr = w >> 1, wc = w & 1;

    v4f acc[4][4] = {};

    for (int kt = 0; kt < 16; ++kt) {
        const int kk = kt * 64;
        __syncthreads();
#pragma unroll
        for (int i = 0; i < 4; ++i) {
            int ci = i * 256 + tid;
            int row = ci >> 3, c = ci & 7;
            async16((char*)As + (size_t)(i * 256 + w * 64) * 16,
                    A + (size_t)(m0 + row) * 1024 + kk + c * 8);
            async16((char*)Bs + (size_t)(i * 256 + w * 64) * 16,
                    BT + (size_t)(n0 + row) * 1024 + kk + c * 8);
        }
        __syncthreads();
#pragma unroll
        for (int ks = 0; ks < 2; ++ks) {
            v8s af[4], bfr[4];
#pragma unroll
            for (int mt = 0; mt < 4; ++mt)
                af[mt] = *(const v8s*)(As + (wr * 64 + mt * 16 + ql) * 64 + ks * 32 + g * 8);
#pragma unroll
            for (int nt = 0; nt < 4; ++nt)
                bfr[nt] = *(const v8s*)(Bs + (wc * 64 + nt * 16 + ql) * 64 + ks * 32 + g * 8);
#pragma unroll
            for (int mt = 0; mt < 4; ++mt)
#pragma unroll
                for (int nt = 0; nt < 4; ++nt)
                    acc[mt][nt] = MFMA16(af[mt], bfr[nt], acc[mt][nt]);
        }
    }

#pragma unroll
    for (int nt = 0; nt < 4; ++nt) {
        int col = n0 + wc * 64 + nt * 16 + ql;
        float bval = bias[col];
        int hh = col >> 6, dd = col & 63;
#pragma unroll
        for (int mt = 0; mt < 4; ++mt) {
#pragma unroll
            for (int r = 0; r < 4; ++r) {
                int gm = m0 + wr * 64 + mt * 16 + g * 4 + r;
                int bb = gm >> 11, ss = gm & 2047;
                float vv = acc[mt][nt][r] + bval;
                if (z == 0) {
                    vv *= 0.125f * LOG2E;  // 1/sqrt(64) * log2e folded into Q
                    QW[((size_t)(bb * NH + hh) * S_LEN + ss) * 64 + dd] = f2bf(vv);
                } else if (z == 1) {
                    KW[((size_t)(bb * NH + hh) * S_LEN + ss) * 64 + dd] = f2bf(vv);
                } else {
                    VT[((size_t)(bb * NH + hh) * 64 + dd) * S_LEN + ss] = f2bf(vv);
                }
            }
        }
    }
}

// ---------------- flash attention ----------------
// grid (16 q-blocks of 128 rows, 64 b*h). 8 waves x 16 q-rows. KVBLK=64.
// Swapped QK^T (lane owns one q-row), exp2-domain softmax, T14 dbuf reg
// staging, st_16x32 LDS swizzle, T5 setprio.
__global__ __launch_bounds__(512)
void attn_kernel(const short* __restrict__ QW, const short* __restrict__ KW,
                 const short* __restrict__ VT, const int* __restrict__ v_mask,
                 short* __restrict__ O) {
    __shared__ short Ks[64 * 64];    // [kp][d], st_16x32 swizzled
    __shared__ short Vs[64 * 64];    // [d][kp], st_16x32 swizzled
    __shared__ short Ps[8][16 * 64]; // per-wave P [q][kp], swizzled
    __shared__ float pf[64];         // (1-vm)*C2MASK penalty per key
    __shared__ int rflag;

    const int tid = threadIdx.x;
    const int l = tid & 63, w = tid >> 6;
    const int g = l >> 4, ql = l & 15;
    const int qb = blockIdx.x, bh = blockIdx.y;
    const int b = bh >> 4, hd = bh & 15;
    const int qw0 = qb * 128 + w * 16;     // this wave's first q-row
    const int q_glob = qw0 + ql;           // this lane's q-row

    const short* Qp = QW + (size_t)bh * S_LEN * 64;
    const short* Kp = KW + (size_t)bh * S_LEN * 64;
    const short* Vp = VT + (size_t)bh * 64 * S_LEN;
    const int* vm = v_mask + b * S_LEN;

    // Q fragment (B-operand of swapped QK^T)
    v8s qf[2];
#pragma unroll
    for (int ks = 0; ks < 2; ++ks)
        qf[ks] = *(const v8s*)(Qp + (size_t)q_glob * 64 + ks * 32 + g * 8);

    v4f accO[4] = {};
    float m_run = -INFINITY, l_run = 0.f;
    short* Pw = Ps[w];

    // staging: 512 threads, 1x16B chunk per tensor each (tile = 64x64 bf16 = 8KB)
    const int r0 = tid >> 3, c0 = tid & 7;
    v8s kA, vA, kB, vB;
    int vmA = 0, vmB = 0;

    auto gload = [&](int kt, v8s& K, v8s& V, int& VM) {
        const int k0 = kt * 64;
        K = *(const v8s*)(Kp + (size_t)(k0 + r0) * 64 + c0 * 8);
        V = *(const v8s*)(Vp + (size_t)r0 * S_LEN + k0 + c0 * 8);
        VM = (tid < 64) ? vm[k0 + tid] : 0;
    };
    auto swrite = [&](v8s& K, v8s& V, int VM) {
        int b0 = r0 * 128 + c0 * 16;
        *(v8s*)((char*)Ks + swz(b0)) = K;
        *(v8s*)((char*)Vs + swz(b0)) = V;
        if (tid < 64) pf[tid] = (1.0f - (float)VM) * C2MASK;
    };

    auto chalf = [&](int kt, bool causal) {
        v4f s4[4] = {};
        __builtin_amdgcn_s_setprio(1);
#pragma unroll
        for (int ks = 0; ks < 2; ++ks)
#pragma unroll
            for (int mt = 0; mt < 4; ++mt) {
                v8s ak = *(const v8s*)((char*)Ks + swz((mt * 16 + ql) * 128 + ks * 64 + g * 16));
                s4[mt] = MFMA16(ak, qf[ks], s4[mt]);
            }
        __builtin_amdgcn_s_setprio(0);
        float tmax = -INFINITY;
#pragma unroll
        for (int mt = 0; mt < 4; ++mt) {
            v4f pen = *(const v4f*)(pf + mt * 16 + g * 4);
#pragma unroll
            for (int r = 0; r < 4; ++r) {
                float s = s4[mt][r] - pen[r];
                if (causal && (kt * 64 + mt * 16 + g * 4 + r > q_glob)) s -= C2MASK;
                s4[mt][r] = s;
                tmax = fmaxf(tmax, s);
            }
        }
        tmax = fmaxf(tmax, __shfl_xor(tmax, 16, 64));
        tmax = fmaxf(tmax, __shfl_xor(tmax, 32, 64));
        float mnew = fmaxf(m_run, tmax);
        float scale = exp2f(m_run - mnew);
        float psum = 0.f;
#pragma unroll
        for (int mt = 0; mt < 4; ++mt)
#pragma unroll
            for (int r = 0; r < 4; ++r) {
                float p = exp2f(s4[mt][r] - mnew);
                s4[mt][r] = p;
                psum += p;
            }
        psum += __shfl_xor(psum, 16, 64);
        psum += __shfl_xor(psum, 32, 64);
        l_run = l_run * scale + psum;
        m_run = mnew;
#pragma unroll
        for (int r = 0; r < 4; ++r) {
            float sc = __shfl(scale, g * 4 + r, 64);
#pragma unroll
            for (int nt = 0; nt < 4; ++nt) accO[nt][r] *= sc;
        }
        // P -> per-wave LDS [q][kp]
#pragma unroll
        for (int mt = 0; mt < 4; ++mt) {
            v4s pk;
#pragma unroll
            for (int r = 0; r < 4; ++r) pk[r] = f2bf(s4[mt][r]);
            *(v4s*)((char*)Pw + swz(ql * 128 + mt * 32 + g * 8)) = pk;
        }
        // PV: A = P[q][kp], B = V[kp][d] via Vs=[d][kp]
        __builtin_amdgcn_s_setprio(1);
#pragma unroll
        for (int ks = 0; ks < 2; ++ks) {
            v8s ap = *(const v8s*)((char*)Pw + swz(ql * 128 + ks * 64 + g * 16));
#pragma unroll
            for (int nt = 0; nt < 4; ++nt) {
                v8s bv = *(const v8s*)((char*)Vs + swz((nt * 16 + ql) * 128 + ks * 64 + g * 16));
                accO[nt] = MFMA16(ap, bv, accO[nt]);
            }
        }
        __builtin_amdgcn_s_setprio(0);
    };

    // main causal loop with double-buffered prefetch (T14)
    const int last = 2 * qb + 1;
    gload(0, kA, vA, vmA);
    for (int kt = 0; kt <= last; ++kt) {
        __syncthreads();
        if (kt & 1) swrite(kB, vB, vmB);
        else        swrite(kA, vA, vmA);
        __syncthreads();
        if (kt < last) {
            if (kt & 1) gload(kt + 1, kA, vA, vmA);
            else        gload(kt + 1, kB, vB, vmB);
        }
        chalf(kt, kt * 64 + 63 > qw0);
    }

    // Rescue pass: rows whose causal-valid keys are ALL masked must tie with
    // future keys at exactly -C2MASK (fp32 reference semantics).
    for (int kt = last + 1; kt < 32; ++kt) {
        if (tid == 0) rflag = 0;
        __syncthreads();
        if (__any(m_run < -1e11f) && l == 0) rflag = 1;
        __syncthreads();
        if (!rflag) break;
        gload(kt, kA, vA, vmA);
        swrite(kA, vA, vmA);
        __syncthreads();
        chalf(kt, true);
    }

    // epilogue: O rows q' = g*4+r, cols d = nt*16+ql
#pragma unroll
    for (int r = 0; r < 4; ++r) {
        float inv = 1.0f / __shfl(l_run, g * 4 + r, 64);
        int s_row = qw0 + g * 4 + r;
#pragma unroll
        for (int nt = 0; nt < 4; ++nt) {
            float v = accO[nt][r] * inv;
            O[(size_t)(b * S_LEN + s_row) * 1024 + hd * 64 + nt * 16 + ql] = f2bf(v);
        }
    }
}

// ---------------- output projection + bias + q_mask ----------------
__global__ __launch_bounds__(256)
void out_gemm(const short* __restrict__ A, const short* __restrict__ BT,
              const float* __restrict__ bias, const int* __restrict__ qmask,
              float* __restrict__ out) {
    __shared__ short As[128 * 64];
    __shared__ short Bs[128 * 64];
    const int tid = threadIdx.x;
    const int l = tid & 63, w = tid >> 6;
    const int g = l >> 4, ql = l & 15;
    const int m0 = blockIdx.x * 128, n0 = blockIdx.y * 128;
    const int wr = w >> 1, wc = w & 1;

    v4f acc[4][4] = {};

    for (int kt = 0; kt < 16; ++kt) {
        const int kk = kt * 64;
        __syncthreads();
#pragma unroll
        for (int i = 0; i < 4; ++i) {
            int ci = i * 256 + tid;
            int row = ci >> 3, c = ci & 7;
            async16((char*)As + (size_t)(i * 256 + w * 64) * 16,
                    A + (size_t)(m0 + row) * 1024 + kk + c * 8);
            async16((char*)Bs + (size_t)(i * 256 + w * 64) * 16,
                    BT + (size_t)(n0 + row) * 1024 + kk + c * 8);
        }
        __syncthreads();
#pragma unroll
        for (int ks = 0; ks < 2; ++ks) {
            v8s af[4], bfr[4];
#pragma unroll
            for (int mt = 0; mt < 4; ++mt)
                af[mt] = *(const v8s*)(As + (wr * 64 + mt * 16 + ql) * 64 + ks * 32 + g * 8);
#pragma unroll
            for (int nt = 0; nt < 4; ++nt)
                bfr[nt] = *(const v8s*)(Bs + (wc * 64 + nt * 16 + ql) * 64 + ks * 32 + g * 8);
#pragma unroll
            for (int mt = 0; mt < 4; ++mt)
#pragma unroll
                for (int nt = 0; nt < 4; ++nt)
                    acc[mt][nt] = MFMA16(af[mt], bfr[nt], acc[mt][nt]);
        }
    }

#pragma unroll
    for (int nt = 0; nt < 4; ++nt) {
        int col = n0 + wc * 64 + nt * 16 + ql;
        float bval = bias[col];
#pragma unroll
        for (int mt = 0; mt < 4; ++mt) {
#pragma unroll
            for (int r = 0; r < 4; ++r) {
                int gm = m0 + wr * 64 + mt * 16 + g * 4 + r;
                float vv = acc[mt][nt][r] + bval;
                vv *= (float)qmask[gm];
                out[(size_t)gm * 1024 + col] = vv;
            }
        }
    }
}

extern "C" void kernel_launch(void* const* d_in, const int* in_sizes, int n_in,
                              void* d_out, int out_size, void* d_ws, size_t ws_size,
                              hipStream_t stream) {
    (void)in_sizes; (void)n_in; (void)out_size; (void)ws_size;
    const float* q  = (const float*)d_in[0];
    const float* k  = (const float*)d_in[1];
    const float* v  = (const float*)d_in[2];
    const int* qmask = (const int*)d_in[3];
    const int* vmask = (const int*)d_in[4];
    const float* Wq = (const float*)d_in[5];
    const float* bq = (const float*)d_in[6];
    const float* Wk = (const float*)d_in[7];
    const float* bk = (const float*)d_in[8];
    const float* Wv = (const float*)d_in[9];
    const float* bv = (const float*)d_in[10];
    const float* Wo = (const float*)d_in[11];
    const float* bo = (const float*)d_in[12];
    float* out = (float*)d_out;

    char* ws = (char*)d_ws;
    const size_t MB = 1024 * 1024;
    short* Xq  = (short*)(ws + 0 * MB);
    short* Xk  = (short*)(ws + 16 * MB);
    short* Xv  = (short*)(ws + 32 * MB);
    short* WTq = (short*)(ws + 48 * MB);
    short* WTk = (short*)(ws + 50 * MB);
    short* WTv = (short*)(ws + 52 * MB);
    short* WTo = (short*)(ws + 54 * MB);
    short* QW  = (short*)(ws + 56 * MB);
    short* KW  = (short*)(ws + 72 * MB);
    short* VTb = (short*)(ws + 88 * MB);
    short* Ob  = (short*)(ws + 104 * MB);

    convert_f32_bf16<<<4096, 256, 0, stream>>>(q, Xq);
    convert_f32_bf16<<<4096, 256, 0, stream>>>(k, Xk);
    convert_f32_bf16<<<4096, 256, 0, stream>>>(v, Xv);
    transpose_w<<<dim3(32, 32), 256, 0, stream>>>(Wq, WTq);
    transpose_w<<<dim3(32, 32), 256, 0, stream>>>(Wk, WTk);
    transpose_w<<<dim3(32, 32), 256, 0, stream>>>(Wv, WTv);
    transpose_w<<<dim3(32, 32), 256, 0, stream>>>(Wo, WTo);

    proj_gemm<<<dim3(64, 8, 3), 256, 0, stream>>>(Xq, Xk, Xv, WTq, WTk, WTv,
                                                  bq, bk, bv, QW, KW, VTb);
    attn_kernel<<<dim3(16, 64), 512, 0, stream>>>(QW, KW, VTb, vmask, Ob);
    out_gemm<<<dim3(64, 8), 256, 0, stream>>>(Ob, WTo, bo, qmask, out);
}

// Round 3
// 331.523 us; speedup vs baseline: 1.1043x; 1.1043x over previous
//
#include <hip/hip_runtime.h>
#include <hip/hip_bf16.h>

// ---- types ----
typedef __attribute__((ext_vector_type(8))) short v8s;   // 8 x bf16 (MFMA A/B frag)
typedef __attribute__((ext_vector_type(4))) short v4s;   // 4 x bf16
typedef __attribute__((ext_vector_type(4))) float v4f;   // MFMA C/D frag

#define S_LEN 2048
#define NB 4
#define NH 16
#define LOG2E 1.4426950408889634f
#define C2MASK 1.4426950408889634e12f   // 1e12 * log2(e), fp32-collapses small addends

__device__ __forceinline__ short f2bf(float f) {
    __hip_bfloat16 h = __float2bfloat16(f);
    union { __hip_bfloat16 h; short s; } u; u.h = h; return u.s;
}

// XOR swizzle for [R][128B] LDS tiles: row r's bytes rotate among 8 x 16B
// slots -> 16-row fragment reads (same col, rows 0..15) hit 8 slots, 2-way
// = free (m136). Derived for THIS tile geometry (G4 rule).
__device__ __forceinline__ int swz(int row, int col) {
    return (row * 128 + col) ^ ((row & 7) << 4);
}

__device__ __forceinline__ void async16(void* lds, const void* g) {
    __builtin_amdgcn_global_load_lds(
        (const __attribute__((address_space(1))) unsigned int*)g,
        (__attribute__((address_space(3))) unsigned int*)lds, 16, 0, 0);
}

#define MFMA16(a, b, c) __builtin_amdgcn_mfma_f32_16x16x32_bf16((a), (b), (c), 0, 0, 0)

// ---------------- convert fp32 -> bf16 (vectorized, G13) ----------------
__global__ __launch_bounds__(256) void convert_f32_bf16(const float* __restrict__ in,
                                                        short* __restrict__ out) {
    size_t i = ((size_t)blockIdx.x * 256 + threadIdx.x) * 8;
    float4 a = *(const float4*)(in + i);
    float4 b = *(const float4*)(in + i + 4);
    v8s o;
    o[0] = f2bf(a.x); o[1] = f2bf(a.y); o[2] = f2bf(a.z); o[3] = f2bf(a.w);
    o[4] = f2bf(b.x); o[5] = f2bf(b.y); o[6] = f2bf(b.z); o[7] = f2bf(b.w);
    *(v8s*)(out + i) = o;
}

// ---------------- W[K][N] fp32 -> WT[N][K] bf16 ----------------
__global__ __launch_bounds__(256) void transpose_w(const float* __restrict__ W,
                                                   short* __restrict__ WT) {
    __shared__ float tile[32][33];
    int k0 = blockIdx.x * 32, n0 = blockIdx.y * 32;
    int tx = threadIdx.x & 31, ty = threadIdx.x >> 5;  // ty 0..7
#pragma unroll
    for (int i = 0; i < 4; ++i)
        tile[ty + i * 8][tx] = W[(size_t)(k0 + ty + i * 8) * 1024 + n0 + tx];
    __syncthreads();
#pragma unroll
    for (int i = 0; i < 4; ++i)
        WT[(size_t)(n0 + ty + i * 8) * 1024 + k0 + tx] = f2bf(tile[tx][ty + i * 8]);
}

// ---------------- fused QKV projection GEMM (m97 structure) ----------------
__global__ __launch_bounds__(256)
void proj_gemm(const short* __restrict__ Xq, const short* __restrict__ Xk,
               const short* __restrict__ Xv,
               const short* __restrict__ WTq, const short* __restrict__ WTk,
               const short* __restrict__ WTv,
               const float* __restrict__ bq, const float* __restrict__ bk,
               const float* __restrict__ bv,
               short* __restrict__ QW, short* __restrict__ KW, short* __restrict__ VT) {
    __shared__ short As[128 * 64];
    __shared__ short Bs[128 * 64];
    const int tid = threadIdx.x;
    const int l = tid & 63, w = tid >> 6;
    const int g = l >> 4, ql = l & 15;
    const int m0 = blockIdx.x * 128, n0 = blockIdx.y * 128;
    const int z = blockIdx.z;
    const short* A  = (z == 0) ? Xq : (z == 1) ? Xk : Xv;
    const short* BT = (z == 0) ? WTq : (z == 1) ? WTk : WTv;
    const float* bias = (z == 0) ? bq : (z == 1) ? bk : bv;
    const int wr = w >> 1, wc = w & 1;

    v4f acc[4][4] = {};

    for (int kt = 0; kt < 16; ++kt) {
        const int kk = kt * 64;
        __syncthreads();
#pragma unroll
        for (int i = 0; i < 4; ++i) {
            int ci = i * 256 + tid;
            int row = ci >> 3, c = ci & 7;
            async16((char*)As + (size_t)(i * 256 + w * 64) * 16,
                    A + (size_t)(m0 + row) * 1024 + kk + c * 8);
            async16((char*)Bs + (size_t)(i * 256 + w * 64) * 16,
                    BT + (size_t)(n0 + row) * 1024 + kk + c * 8);
        }
        __syncthreads();
#pragma unroll
        for (int ks = 0; ks < 2; ++ks) {
            v8s af[4], bfr[4];
#pragma unroll
            for (int mt = 0; mt < 4; ++mt)
                af[mt] = *(const v8s*)(As + (wr * 64 + mt * 16 + ql) * 64 + ks * 32 + g * 8);
#pragma unroll
            for (int nt = 0; nt < 4; ++nt)
                bfr[nt] = *(const v8s*)(Bs + (wc * 64 + nt * 16 + ql) * 64 + ks * 32 + g * 8);
#pragma unroll
            for (int mt = 0; mt < 4; ++mt)
#pragma unroll
                for (int nt = 0; nt < 4; ++nt)
                    acc[mt][nt] = MFMA16(af[mt], bfr[nt], acc[mt][nt]);
        }
    }

#pragma unroll
    for (int nt = 0; nt < 4; ++nt) {
        int col = n0 + wc * 64 + nt * 16 + ql;
        float bval = bias[col];
        int hh = col >> 6, dd = col & 63;
#pragma unroll
        for (int mt = 0; mt < 4; ++mt) {
#pragma unroll
            for (int r = 0; r < 4; ++r) {
                int gm = m0 + wr * 64 + mt * 16 + g * 4 + r;
                int bb = gm >> 11, ss = gm & 2047;
                float vv = acc[mt][nt][r] + bval;
                if (z == 0) {
                    vv *= 0.125f * LOG2E;  // 1/sqrt(64) * log2e folded into Q
                    QW[((size_t)(bb * NH + hh) * S_LEN + ss) * 64 + dd] = f2bf(vv);
                } else if (z == 1) {
                    KW[((size_t)(bb * NH + hh) * S_LEN + ss) * 64 + dd] = f2bf(vv);
                } else {
                    VT[((size_t)(bb * NH + hh) * 64 + dd) * S_LEN + ss] = f2bf(vv);
                }
            }
        }
    }
}

// ---------------- flash attention ----------------
// grid (8 paired q-blocks, 64 b*h). Block bx handles q-blocks {bx, 15-bx}
// sequentially -> every block does exactly 34 K-tile steps (causal balance).
// 8 waves x 16 q-rows. KVBLK=64. Swapped QK^T, exp2-domain softmax,
// T14 dbuf reg staging, row-XOR LDS swizzle, T5 setprio.
__global__ __launch_bounds__(512)
void attn_kernel(const short* __restrict__ QW, const short* __restrict__ KW,
                 const short* __restrict__ VT, const int* __restrict__ v_mask,
                 short* __restrict__ O) {
    __shared__ short Ks[64 * 64];    // [kp][d], row-XOR swizzled
    __shared__ short Vs[64 * 64];    // [d][kp], row-XOR swizzled
    __shared__ short Ps[8][16 * 64]; // per-wave P [q][kp], swizzled
    __shared__ float pf[64];         // (1-vm)*C2MASK penalty per key
    __shared__ int rflag;

    const int tid = threadIdx.x;
    const int l = tid & 63, w = tid >> 6;
    const int g = l >> 4, ql = l & 15;
    const int bx = blockIdx.x, bh = blockIdx.y;
    const int b = bh >> 4, hd = bh & 15;

    const short* Qp = QW + (size_t)bh * S_LEN * 64;
    const short* Kp = KW + (size_t)bh * S_LEN * 64;
    const short* Vp = VT + (size_t)bh * 64 * S_LEN;
    const int* vm = v_mask + b * S_LEN;
    short* Pw = Ps[w];

    // staging: 512 threads, 1x16B chunk per tensor each (tile = 64x64 bf16 = 8KB)
    const int r0 = tid >> 3, c0 = tid & 7;

    for (int half = 0; half < 2; ++half) {
        const int qb = half ? (15 - bx) : bx;
        const int qw0 = qb * 128 + w * 16;     // this wave's first q-row
        const int q_glob = qw0 + ql;           // this lane's q-row

        // Q fragment (B-operand of swapped QK^T)
        v8s qf[2];
#pragma unroll
        for (int ks = 0; ks < 2; ++ks)
            qf[ks] = *(const v8s*)(Qp + (size_t)q_glob * 64 + ks * 32 + g * 8);

        v4f accO[4] = {};
        float m_run = -INFINITY, l_run = 0.f;
        v8s kA, vA, kB, vB;
        int vmA = 0, vmB = 0;

        auto gload = [&](int kt, v8s& K, v8s& V, int& VM) {
            const int k0 = kt * 64;
            K = *(const v8s*)(Kp + (size_t)(k0 + r0) * 64 + c0 * 8);
            V = *(const v8s*)(Vp + (size_t)r0 * S_LEN + k0 + c0 * 8);
            VM = (tid < 64) ? vm[k0 + tid] : 0;
        };
        auto swrite = [&](v8s& K, v8s& V, int VM) {
            *(v8s*)((char*)Ks + swz(r0, c0 * 16)) = K;
            *(v8s*)((char*)Vs + swz(r0, c0 * 16)) = V;
            if (tid < 64) pf[tid] = (1.0f - (float)VM) * C2MASK;
        };

        auto chalf = [&](int kt, bool causal) {
            v4f s4[4] = {};
            __builtin_amdgcn_s_setprio(1);
#pragma unroll
            for (int ks = 0; ks < 2; ++ks)
#pragma unroll
                for (int mt = 0; mt < 4; ++mt) {
                    v8s ak = *(const v8s*)((char*)Ks + swz(mt * 16 + ql, ks * 64 + g * 16));
                    s4[mt] = MFMA16(ak, qf[ks], s4[mt]);
                }
            __builtin_amdgcn_s_setprio(0);
            float tmax = -INFINITY;
#pragma unroll
            for (int mt = 0; mt < 4; ++mt) {
                v4f pen = *(const v4f*)(pf + mt * 16 + g * 4);
#pragma unroll
                for (int r = 0; r < 4; ++r) {
                    float s = s4[mt][r] - pen[r];
                    if (causal && (kt * 64 + mt * 16 + g * 4 + r > q_glob)) s -= C2MASK;
                    s4[mt][r] = s;
                    tmax = fmaxf(tmax, s);
                }
            }
            tmax = fmaxf(tmax, __shfl_xor(tmax, 16, 64));
            tmax = fmaxf(tmax, __shfl_xor(tmax, 32, 64));
            float mnew = fmaxf(m_run, tmax);
            float scale = exp2f(m_run - mnew);
            float psum = 0.f;
#pragma unroll
            for (int mt = 0; mt < 4; ++mt)
#pragma unroll
                for (int r = 0; r < 4; ++r) {
                    float p = exp2f(s4[mt][r] - mnew);
                    s4[mt][r] = p;
                    psum += p;
                }
            psum += __shfl_xor(psum, 16, 64);
            psum += __shfl_xor(psum, 32, 64);
            l_run = l_run * scale + psum;
            m_run = mnew;
#pragma unroll
            for (int r = 0; r < 4; ++r) {
                float sc = __shfl(scale, g * 4 + r, 64);
#pragma unroll
                for (int nt = 0; nt < 4; ++nt) accO[nt][r] *= sc;
            }
            // P -> per-wave LDS [q][kp]
#pragma unroll
            for (int mt = 0; mt < 4; ++mt) {
                v4s pk;
#pragma unroll
                for (int r = 0; r < 4; ++r) pk[r] = f2bf(s4[mt][r]);
                *(v4s*)((char*)Pw + swz(ql, mt * 32 + g * 8)) = pk;
            }
            // PV: A = P[q][kp], B = V[kp][d] via Vs=[d][kp]
            __builtin_amdgcn_s_setprio(1);
#pragma unroll
            for (int ks = 0; ks < 2; ++ks) {
                v8s ap = *(const v8s*)((char*)Pw + swz(ql, ks * 64 + g * 16));
#pragma unroll
                for (int nt = 0; nt < 4; ++nt) {
                    v8s bv = *(const v8s*)((char*)Vs + swz(nt * 16 + ql, ks * 64 + g * 16));
                    accO[nt] = MFMA16(ap, bv, accO[nt]);
                }
            }
            __builtin_amdgcn_s_setprio(0);
        };

        // main causal loop with double-buffered prefetch (T14)
        const int last = 2 * qb + 1;
        gload(0, kA, vA, vmA);
        for (int kt = 0; kt <= last; ++kt) {
            __syncthreads();
            if (kt & 1) swrite(kB, vB, vmB);
            else        swrite(kA, vA, vmA);
            __syncthreads();
            if (kt < last) {
                if (kt & 1) gload(kt + 1, kA, vA, vmA);
                else        gload(kt + 1, kB, vB, vmB);
            }
            chalf(kt, kt * 64 + 63 > qw0);
        }

        // Rescue pass: rows whose causal-valid keys are ALL masked must tie
        // with future keys at exactly -C2MASK (fp32 reference semantics).
        for (int kt = last + 1; kt < 32; ++kt) {
            if (tid == 0) rflag = 0;
            __syncthreads();
            if (__any(m_run < -1e11f) && l == 0) rflag = 1;
            __syncthreads();
            if (!rflag) break;
            gload(kt, kA, vA, vmA);
            swrite(kA, vA, vmA);
            __syncthreads();
            chalf(kt, true);
        }

        // epilogue: O rows q' = g*4+r, cols d = nt*16+ql
#pragma unroll
        for (int r = 0; r < 4; ++r) {
            float inv = 1.0f / __shfl(l_run, g * 4 + r, 64);
            int s_row = qw0 + g * 4 + r;
#pragma unroll
            for (int nt = 0; nt < 4; ++nt) {
                float v = accO[nt][r] * inv;
                O[(size_t)(b * S_LEN + s_row) * 1024 + hd * 64 + nt * 16 + ql] = f2bf(v);
            }
        }
    }
}

// ---------------- output projection + bias + q_mask ----------------
__global__ __launch_bounds__(256)
void out_gemm(const short* __restrict__ A, const short* __restrict__ BT,
              const float* __restrict__ bias, const int* __restrict__ qmask,
              float* __restrict__ out) {
    __shared__ short As[128 * 64];
    __shared__ short Bs[128 * 64];
    const int tid = threadIdx.x;
    const int l = tid & 63, w = tid >> 6;
    const int g = l >> 4, ql = l & 15;
    const int m0 = blockIdx.x * 128, n0 = blockIdx.y * 128;
    const int wr = w >> 1, wc = w & 1;

    v4f acc[4][4] = {};

    for (int kt = 0; kt < 16; ++kt) {
        const int kk = kt * 64;
        __syncthreads();
#pragma unroll
        for (int i = 0; i < 4; ++i) {
            int ci = i * 256 + tid;
            int row = ci >> 3, c = ci & 7;
            async16((char*)As + (size_t)(i * 256 + w * 64) * 16,
                    A + (size_t)(m0 + row) * 1024 + kk + c * 8);
            async16((char*)Bs + (size_t)(i * 256 + w * 64) * 16,
                    BT + (size_t)(n0 + row) * 1024 + kk + c * 8);
        }
        __syncthreads();
#pragma unroll
        for (int ks = 0; ks < 2; ++ks) {
            v8s af[4], bfr[4];
#pragma unroll
            for (int mt = 0; mt < 4; ++mt)
                af[mt] = *(const v8s*)(As + (wr * 64 + mt * 16 + ql) * 64 + ks * 32 + g * 8);
#pragma unroll
            for (int nt = 0; nt < 4; ++nt)
                bfr[nt] = *(const v8s*)(Bs + (wc * 64 + nt * 16 + ql) * 64 + ks * 32 + g * 8);
#pragma unroll
            for (int mt = 0; mt < 4; ++mt)
#pragma unroll
                for (int nt = 0; nt < 4; ++nt)
                    acc[mt][nt] = MFMA16(af[mt], bfr[nt], acc[mt][nt]);
        }
    }

#pragma unroll
    for (int nt = 0; nt < 4; ++nt) {
        int col = n0 + wc * 64 + nt * 16 + ql;
        float bval = bias[col];
#pragma unroll
        for (int mt = 0; mt < 4; ++mt) {
#pragma unroll
            for (int r = 0; r < 4; ++r) {
                int gm = m0 + wr * 64 + mt * 16 + g * 4 + r;
                float vv = acc[mt][nt][r] + bval;
                vv *= (float)qmask[gm];
                out[(size_t)gm * 1024 + col] = vv;
            }
        }
    }
}

extern "C" void kernel_launch(void* const* d_in, const int* in_sizes, int n_in,
                              void* d_out, int out_size, void* d_ws, size_t ws_size,
                              hipStream_t stream) {
    (void)in_sizes; (void)n_in; (void)out_size; (void)ws_size;
    const float* q  = (const float*)d_in[0];
    const float* k  = (const float*)d_in[1];
    const float* v  = (const float*)d_in[2];
    const int* qmask = (const int*)d_in[3];
    const int* vmask = (const int*)d_in[4];
    const float* Wq = (const float*)d_in[5];
    const float* bq = (const float*)d_in[6];
    const float* Wk = (const float*)d_in[7];
    const float* bk = (const float*)d_in[8];
    const float* Wv = (const float*)d_in[9];
    const float* bv = (const float*)d_in[10];
    const float* Wo = (const float*)d_in[11];
    const float* bo = (const float*)d_in[12];
    float* out = (float*)d_out;

    char* ws = (char*)d_ws;
    const size_t MB = 1024 * 1024;
    short* Xq  = (short*)(ws + 0 * MB);
    short* Xk  = (short*)(ws + 16 * MB);
    short* Xv  = (short*)(ws + 32 * MB);
    short* WTq = (short*)(ws + 48 * MB);
    short* WTk = (short*)(ws + 50 * MB);
    short* WTv = (short*)(ws + 52 * MB);
    short* WTo = (short*)(ws + 54 * MB);
    short* QW  = (short*)(ws + 56 * MB);
    short* KW  = (short*)(ws + 72 * MB);
    short* VTb = (short*)(ws + 88 * MB);
    short* Ob  = (short*)(ws + 104 * MB);

    convert_f32_bf16<<<4096, 256, 0, stream>>>(q, Xq);
    convert_f32_bf16<<<4096, 256, 0, stream>>>(k, Xk);
    convert_f32_bf16<<<4096, 256, 0, stream>>>(v, Xv);
    transpose_w<<<dim3(32, 32), 256, 0, stream>>>(Wq, WTq);
    transpose_w<<<dim3(32, 32), 256, 0, stream>>>(Wk, WTk);
    transpose_w<<<dim3(32, 32), 256, 0, stream>>>(Wv, WTv);
    transpose_w<<<dim3(32, 32), 256, 0, stream>>>(Wo, WTo);

    proj_gemm<<<dim3(64, 8, 3), 256, 0, stream>>>(Xq, Xk, Xv, WTq, WTk, WTv,
                                                  bq, bk, bv, QW, KW, VTb);
    attn_kernel<<<dim3(8, 64), 512, 0, stream>>>(QW, KW, VTb, vmask, Ob);
    out_gemm<<<dim3(64, 8), 256, 0, stream>>>(Ob, WTo, bo, qmask, out);
}

// Round 4
// 316.974 us; speedup vs baseline: 1.1549x; 1.0459x over previous
//
#include <hip/hip_runtime.h>
#include <hip/hip_bf16.h>

// ---- types ----
typedef __attribute__((ext_vector_type(8))) short v8s;   // 8 x bf16
typedef __attribute__((ext_vector_type(4))) short v4s;   // 4 x bf16
typedef __attribute__((ext_vector_type(4))) float v4f;
typedef __attribute__((ext_vector_type(16))) float v16f; // 32x32 MFMA C/D
typedef __attribute__((ext_vector_type(4))) unsigned v4u;

#define S_LEN 2048
#define NB 4
#define NH 16
#define LOG2E 1.4426950408889634f
#define C2MASK 1.4426950408889634e12f   // 1e12 * log2(e), fp32-collapses small addends
#define DEFER_THR 11.55f                // 8 * log2(e)  (T13)

__device__ __forceinline__ short f2bf(float f) {
    __hip_bfloat16 h = __float2bfloat16(f);
    union { __hip_bfloat16 h; short s; } u; u.h = h; return u.s;
}

__device__ __forceinline__ unsigned cvtpk(float lo, float hi) {
    unsigned r;
    asm("v_cvt_pk_bf16_f32 %0, %1, %2" : "=v"(r) : "v"(lo), "v"(hi));
    return r;
}

// XOR swizzle for [R][128B] LDS tiles. 32 rows x same col -> 8 groups (row&7)
// x 4 banks each = all 32 banks tiled exactly -> conflict-free b128 reads.
__device__ __forceinline__ int swz(int row, int col) {
    return (row * 128 + col) ^ ((row & 7) << 4);
}

__device__ __forceinline__ void async16(void* lds, const void* g) {
    __builtin_amdgcn_global_load_lds(
        (const __attribute__((address_space(1))) unsigned int*)g,
        (__attribute__((address_space(3))) unsigned int*)lds, 16, 0, 0);
}

#define MFMA16(a, b, c) __builtin_amdgcn_mfma_f32_16x16x32_bf16((a), (b), (c), 0, 0, 0)
#define MFMA32(a, b, c) __builtin_amdgcn_mfma_f32_32x32x16_bf16((a), (b), (c), 0, 0, 0)

// ---------------- convert fp32 -> bf16 (vectorized, G13) ----------------
__global__ __launch_bounds__(256) void convert_f32_bf16(const float* __restrict__ in,
                                                        short* __restrict__ out) {
    size_t i = ((size_t)blockIdx.x * 256 + threadIdx.x) * 8;
    float4 a = *(const float4*)(in + i);
    float4 b = *(const float4*)(in + i + 4);
    v8s o;
    o[0] = f2bf(a.x); o[1] = f2bf(a.y); o[2] = f2bf(a.z); o[3] = f2bf(a.w);
    o[4] = f2bf(b.x); o[5] = f2bf(b.y); o[6] = f2bf(b.z); o[7] = f2bf(b.w);
    *(v8s*)(out + i) = o;
}

// ---------------- W[K][N] fp32 -> WT[N][K] bf16 ----------------
__global__ __launch_bounds__(256) void transpose_w(const float* __restrict__ W,
                                                   short* __restrict__ WT) {
    __shared__ float tile[32][33];
    int k0 = blockIdx.x * 32, n0 = blockIdx.y * 32;
    int tx = threadIdx.x & 31, ty = threadIdx.x >> 5;  // ty 0..7
#pragma unroll
    for (int i = 0; i < 4; ++i)
        tile[ty + i * 8][tx] = W[(size_t)(k0 + ty + i * 8) * 1024 + n0 + tx];
    __syncthreads();
#pragma unroll
    for (int i = 0; i < 4; ++i)
        WT[(size_t)(n0 + ty + i * 8) * 1024 + k0 + tx] = f2bf(tile[tx][ty + i * 8]);
}

// ---------------- fused QKV projection GEMM (m97 structure) ----------------
__global__ __launch_bounds__(256)
void proj_gemm(const short* __restrict__ Xq, const short* __restrict__ Xk,
               const short* __restrict__ Xv,
               const short* __restrict__ WTq, const short* __restrict__ WTk,
               const short* __restrict__ WTv,
               const float* __restrict__ bq, const float* __restrict__ bk,
               const float* __restrict__ bv,
               short* __restrict__ QW, short* __restrict__ KW, short* __restrict__ VT) {
    __shared__ short As[128 * 64];
    __shared__ short Bs[128 * 64];
    const int tid = threadIdx.x;
    const int l = tid & 63, w = tid >> 6;
    const int g = l >> 4, ql = l & 15;
    const int m0 = blockIdx.x * 128, n0 = blockIdx.y * 128;
    const int z = blockIdx.z;
    const short* A  = (z == 0) ? Xq : (z == 1) ? Xk : Xv;
    const short* BT = (z == 0) ? WTq : (z == 1) ? WTk : WTv;
    const float* bias = (z == 0) ? bq : (z == 1) ? bk : bv;
    const int wr = w >> 1, wc = w & 1;

    v4f acc[4][4] = {};

    for (int kt = 0; kt < 16; ++kt) {
        const int kk = kt * 64;
        __syncthreads();
#pragma unroll
        for (int i = 0; i < 4; ++i) {
            int ci = i * 256 + tid;
            int row = ci >> 3, c = ci & 7;
            async16((char*)As + (size_t)(i * 256 + w * 64) * 16,
                    A + (size_t)(m0 + row) * 1024 + kk + c * 8);
            async16((char*)Bs + (size_t)(i * 256 + w * 64) * 16,
                    BT + (size_t)(n0 + row) * 1024 + kk + c * 8);
        }
        __syncthreads();
#pragma unroll
        for (int ks = 0; ks < 2; ++ks) {
            v8s af[4], bfr[4];
#pragma unroll
            for (int mt = 0; mt < 4; ++mt)
                af[mt] = *(const v8s*)(As + (wr * 64 + mt * 16 + ql) * 64 + ks * 32 + g * 8);
#pragma unroll
            for (int nt = 0; nt < 4; ++nt)
                bfr[nt] = *(const v8s*)(Bs + (wc * 64 + nt * 16 + ql) * 64 + ks * 32 + g * 8);
#pragma unroll
            for (int mt = 0; mt < 4; ++mt)
#pragma unroll
                for (int nt = 0; nt < 4; ++nt)
                    acc[mt][nt] = MFMA16(af[mt], bfr[nt], acc[mt][nt]);
        }
    }

#pragma unroll
    for (int nt = 0; nt < 4; ++nt) {
        int col = n0 + wc * 64 + nt * 16 + ql;
        float bval = bias[col];
        int hh = col >> 6, dd = col & 63;
#pragma unroll
        for (int mt = 0; mt < 4; ++mt) {
#pragma unroll
            for (int r = 0; r < 4; ++r) {
                int gm = m0 + wr * 64 + mt * 16 + g * 4 + r;
                int bb = gm >> 11, ss = gm & 2047;
                float vv = acc[mt][nt][r] + bval;
                if (z == 0) {
                    vv *= 0.125f * LOG2E;  // 1/sqrt(64) * log2e folded into Q
                    QW[((size_t)(bb * NH + hh) * S_LEN + ss) * 64 + dd] = f2bf(vv);
                } else if (z == 1) {
                    KW[((size_t)(bb * NH + hh) * S_LEN + ss) * 64 + dd] = f2bf(vv);
                } else {
                    VT[((size_t)(bb * NH + hh) * 64 + dd) * S_LEN + ss] = f2bf(vv);
                }
            }
        }
    }
}

// ---------------- flash attention (m214-style 8-warp 32x32) ----------------
// grid (64 bh, 4 bx); block bx handles q-blocks {bx, 7-bx} of 256 rows each
// -> 36 K-tiles per block, balanced. 8 waves x 32 q-rows. KVBLK=64.
// Swapped QK^T (32x32x16), in-register P via cvt_pk+permlane32_swap,
// LDS double-buffer (1 barrier/tile), T13 defer-max, T5 setprio.
__global__ __launch_bounds__(512)
void attn_kernel(const short* __restrict__ QW, const short* __restrict__ KW,
                 const short* __restrict__ VT, const int* __restrict__ v_mask,
                 short* __restrict__ O) {
    __shared__ short Ks[2][64 * 64];  // [kp][d], row-XOR swizzled
    __shared__ short Vs[2][64 * 64];  // [d][kp], row-XOR swizzled
    __shared__ float pf[2][64];       // (1-vm)*C2MASK penalty per key
    __shared__ int rflag;

    const int tid = threadIdx.x;
    const int l = tid & 63, w = tid >> 6;
    const int lq = l & 31, hi = l >> 5;
    const int bh = blockIdx.x, bx = blockIdx.y;
    const int b = bh >> 4, hd = bh & 15;

    const short* Qp = QW + (size_t)bh * S_LEN * 64;
    const short* Kp = KW + (size_t)bh * S_LEN * 64;
    const short* Vp = VT + (size_t)bh * 64 * S_LEN;
    const int* vm = v_mask + b * S_LEN;

    const int r0 = tid >> 3, c0 = tid & 7;  // staging coords (64 rows x 8 v8s)

    for (int half = 0; half < 2; ++half) {
        const int qb = half ? (7 - bx) : bx;
        const int qw0 = qb * 256 + w * 32;   // this wave's first q-row
        const int q_glob = qw0 + lq;         // this lane's q-row

        // Q fragments (B-operand of swapped QK^T): col=q (lq), k = ks*16+hi*8+j
        v8s qf[4];
#pragma unroll
        for (int ks = 0; ks < 4; ++ks)
            qf[ks] = *(const v8s*)(Qp + (size_t)q_glob * 64 + ks * 16 + hi * 8);

        v16f accO[2] = {};
        float m_run = -INFINITY, l_run = 0.f;

        v8s kA, vA; int vmA = 0;

        auto gload = [&](int kt) {
            const int k0 = kt * 64;
            kA = *(const v8s*)(Kp + (size_t)(k0 + r0) * 64 + c0 * 8);
            vA = *(const v8s*)(Vp + (size_t)r0 * S_LEN + k0 + c0 * 8);
            vmA = (tid < 64) ? vm[k0 + tid] : 0;
        };
        auto swrite = [&](int buf) {
            *(v8s*)((char*)Ks[buf] + swz(r0, c0 * 16)) = kA;
            *(v8s*)((char*)Vs[buf] + swz(r0, c0 * 16)) = vA;
            if (tid < 64) pf[buf][tid] = (1.0f - (float)vmA) * C2MASK;
        };

        auto chalf = [&](int kt, int buf, bool causal) {
            const int k0 = kt * 64;
            const short* Kb = Ks[buf];
            const short* Vb = Vs[buf];
            const float* pb = pf[buf];

            // QK^T: A=K rows(kp), B=Q. acc[t]: kp tile t*32, lane col q=lq,
            // rows kp = t*32 + (j&3)+8*(j>>2)+4*hi
            v16f acc[2] = {};
            __builtin_amdgcn_s_setprio(1);
#pragma unroll
            for (int ks = 0; ks < 4; ++ks) {
                v8s k0f = *(const v8s*)((char*)Kb + swz(lq, ks * 32 + hi * 16));
                v8s k1f = *(const v8s*)((char*)Kb + swz(32 + lq, ks * 32 + hi * 16));
                acc[0] = MFMA32(k0f, qf[ks], acc[0]);
                acc[1] = MFMA32(k1f, qf[ks], acc[1]);
            }
            __builtin_amdgcn_s_setprio(0);

            // penalties (broadcast v4f reads) + optional causal, then row max
            float s[32];
            float tmax = -INFINITY;
#pragma unroll
            for (int t = 0; t < 2; ++t)
#pragma unroll
                for (int a = 0; a < 4; ++a) {
                    v4f pen = *(const v4f*)(pb + t * 32 + a * 8 + hi * 4);
#pragma unroll
                    for (int r = 0; r < 4; ++r)
                        s[t * 16 + a * 4 + r] = acc[t][a * 4 + r] - pen[r];
                }
            if (causal) {
#pragma unroll
                for (int t = 0; t < 2; ++t)
#pragma unroll
                    for (int j = 0; j < 16; ++j) {
                        int kp = k0 + t * 32 + (j & 3) + 8 * (j >> 2) + 4 * hi;
                        if (kp > q_glob) s[t * 16 + j] -= C2MASK;
                    }
            }
#pragma unroll
            for (int i = 0; i < 32; ++i) tmax = fmaxf(tmax, s[i]);
            tmax = fmaxf(tmax, __shfl_xor(tmax, 32, 64));

            // T13 defer-max: only rescale when max grew past threshold
            if (__any(tmax > m_run + DEFER_THR)) {
                float mnew = fmaxf(m_run, tmax);
                float scale = exp2f(m_run - mnew);
                m_run = mnew;
                l_run *= scale;
#pragma unroll
                for (int j = 0; j < 16; ++j) {
                    float sc = __shfl(scale, (j & 3) + 8 * (j >> 2) + 4 * hi, 64);
                    accO[0][j] *= sc;
                    accO[1][j] *= sc;
                }
            }
            float psum = 0.f;
#pragma unroll
            for (int i = 0; i < 32; ++i) {
                float p = exp2f(s[i] - m_run);
                s[i] = p;
                psum += p;
            }
            psum += __shfl_xor(psum, 32, 64);
            l_run += psum;

            // P -> PV A-operand in registers: cvt_pk pairs + permlane32_swap.
            // Frag ks=t*2+sf elem j: kp = ks*16+hi*8+j; sources: reg
            // (2sf+hi_t)*4+(j&3) of half (j>>2). Two swaps build 4 words.
            v8s PA[4];
#pragma unroll
            for (int t = 0; t < 2; ++t)
#pragma unroll
                for (int sf = 0; sf < 2; ++sf) {
                    int base = t * 16 + sf * 8;
                    unsigned x0 = cvtpk(s[base + 0], s[base + 1]);
                    unsigned x1 = cvtpk(s[base + 2], s[base + 3]);
                    unsigned y0 = cvtpk(s[base + 4], s[base + 5]);
                    unsigned y1 = cvtpk(s[base + 6], s[base + 7]);
                    asm volatile("v_permlane32_swap_b32 %0, %1" : "+v"(x0), "+v"(y0));
                    asm volatile("v_permlane32_swap_b32 %0, %1" : "+v"(x1), "+v"(y1));
                    v4u wv; wv[0] = x0; wv[1] = x1; wv[2] = y0; wv[3] = y1;
                    union { v4u u; v8s s8; } cvt; cvt.u = wv;
                    PA[t * 2 + sf] = cvt.s8;
                }

            // PV: A=P (in-reg), B=V[kp][d] via Vs=[d][kp]
            __builtin_amdgcn_s_setprio(1);
#pragma unroll
            for (int ks = 0; ks < 4; ++ks) {
                v8s v0f = *(const v8s*)((char*)Vb + swz(lq, ks * 32 + hi * 16));
                v8s v1f = *(const v8s*)((char*)Vb + swz(32 + lq, ks * 32 + hi * 16));
                accO[0] = MFMA32(PA[ks], v0f, accO[0]);
                accO[1] = MFMA32(PA[ks], v1f, accO[1]);
            }
            __builtin_amdgcn_s_setprio(0);
        };

        // main causal loop: LDS dbuf, ONE barrier per tile, T14 reg prefetch
        const int last = 4 * qb + 3;
        gload(0);
        __syncthreads();           // protect buffer reuse across halves
        swrite(0);
        gload(1);
        for (int kt = 0; kt <= last; ++kt) {
            __syncthreads();
            if (kt < last) {
                swrite((kt + 1) & 1);
                if (kt + 1 < last) gload(kt + 2);
            }
            chalf(kt, kt & 1, kt * 64 + 63 > qw0);
        }

        // Rescue pass: rows whose causal-valid keys are ALL masked must tie
        // with future keys at exactly -C2MASK (fp32 reference semantics).
        for (int kt = last + 1; kt < 32; ++kt) {
            if (tid == 0) rflag = 0;
            __syncthreads();
            if (__any(m_run < -1e11f) && l == 0) rflag = 1;
            __syncthreads();
            if (!rflag) break;
            gload(kt);
            swrite(0);
            __syncthreads();
            chalf(kt, 0, true);
        }

        // epilogue: rows q=(j&3)+8*(j>>2)+4*hi, cols d = dt*32+lq
        float inv = 1.0f / l_run;
#pragma unroll
        for (int j = 0; j < 16; ++j) {
            int rowq = (j & 3) + 8 * (j >> 2) + 4 * hi;
            float iv = __shfl(inv, rowq, 64);
            size_t base = (size_t)(b * S_LEN + qw0 + rowq) * 1024 + hd * 64 + lq;
            O[base]      = f2bf(accO[0][j] * iv);
            O[base + 32] = f2bf(accO[1][j] * iv);
        }
    }
}

// ---------------- output projection + bias + q_mask ----------------
__global__ __launch_bounds__(256)
void out_gemm(const short* __restrict__ A, const short* __restrict__ BT,
              const float* __restrict__ bias, const int* __restrict__ qmask,
              float* __restrict__ out) {
    __shared__ short As[128 * 64];
    __shared__ short Bs[128 * 64];
    const int tid = threadIdx.x;
    const int l = tid & 63, w = tid >> 6;
    const int g = l >> 4, ql = l & 15;
    const int m0 = blockIdx.x * 128, n0 = blockIdx.y * 128;
    const int wr = w >> 1, wc = w & 1;

    v4f acc[4][4] = {};

    for (int kt = 0; kt < 16; ++kt) {
        const int kk = kt * 64;
        __syncthreads();
#pragma unroll
        for (int i = 0; i < 4; ++i) {
            int ci = i * 256 + tid;
            int row = ci >> 3, c = ci & 7;
            async16((char*)As + (size_t)(i * 256 + w * 64) * 16,
                    A + (size_t)(m0 + row) * 1024 + kk + c * 8);
            async16((char*)Bs + (size_t)(i * 256 + w * 64) * 16,
                    BT + (size_t)(n0 + row) * 1024 + kk + c * 8);
        }
        __syncthreads();
#pragma unroll
        for (int ks = 0; ks < 2; ++ks) {
            v8s af[4], bfr[4];
#pragma unroll
            for (int mt = 0; mt < 4; ++mt)
                af[mt] = *(const v8s*)(As + (wr * 64 + mt * 16 + ql) * 64 + ks * 32 + g * 8);
#pragma unroll
            for (int nt = 0; nt < 4; ++nt)
                bfr[nt] = *(const v8s*)(Bs + (wc * 64 + nt * 16 + ql) * 64 + ks * 32 + g * 8);
#pragma unroll
            for (int mt = 0; mt < 4; ++mt)
#pragma unroll
                for (int nt = 0; nt < 4; ++nt)
                    acc[mt][nt] = MFMA16(af[mt], bfr[nt], acc[mt][nt]);
        }
    }

#pragma unroll
    for (int nt = 0; nt < 4; ++nt) {
        int col = n0 + wc * 64 + nt * 16 + ql;
        float bval = bias[col];
#pragma unroll
        for (int mt = 0; mt < 4; ++mt) {
#pragma unroll
            for (int r = 0; r < 4; ++r) {
                int gm = m0 + wr * 64 + mt * 16 + g * 4 + r;
                float vv = acc[mt][nt][r] + bval;
                vv *= (float)qmask[gm];
                out[(size_t)gm * 1024 + col] = vv;
            }
        }
    }
}

extern "C" void kernel_launch(void* const* d_in, const int* in_sizes, int n_in,
                              void* d_out, int out_size, void* d_ws, size_t ws_size,
                              hipStream_t stream) {
    (void)in_sizes; (void)n_in; (void)out_size; (void)ws_size;
    const float* q  = (const float*)d_in[0];
    const float* k  = (const float*)d_in[1];
    const float* v  = (const float*)d_in[2];
    const int* qmask = (const int*)d_in[3];
    const int* vmask = (const int*)d_in[4];
    const float* Wq = (const float*)d_in[5];
    const float* bq = (const float*)d_in[6];
    const float* Wk = (const float*)d_in[7];
    const float* bk = (const float*)d_in[8];
    const float* Wv = (const float*)d_in[9];
    const float* bv = (const float*)d_in[10];
    const float* Wo = (const float*)d_in[11];
    const float* bo = (const float*)d_in[12];
    float* out = (float*)d_out;

    char* ws = (char*)d_ws;
    const size_t MB = 1024 * 1024;
    short* Xq  = (short*)(ws + 0 * MB);
    short* Xk  = (short*)(ws + 16 * MB);
    short* Xv  = (short*)(ws + 32 * MB);
    short* WTq = (short*)(ws + 48 * MB);
    short* WTk = (short*)(ws + 50 * MB);
    short* WTv = (short*)(ws + 52 * MB);
    short* WTo = (short*)(ws + 54 * MB);
    short* QW  = (short*)(ws + 56 * MB);
    short* KW  = (short*)(ws + 72 * MB);
    short* VTb = (short*)(ws + 88 * MB);
    short* Ob  = (short*)(ws + 104 * MB);

    convert_f32_bf16<<<4096, 256, 0, stream>>>(q, Xq);
    convert_f32_bf16<<<4096, 256, 0, stream>>>(k, Xk);
    convert_f32_bf16<<<4096, 256, 0, stream>>>(v, Xv);
    transpose_w<<<dim3(32, 32), 256, 0, stream>>>(Wq, WTq);
    transpose_w<<<dim3(32, 32), 256, 0, stream>>>(Wk, WTk);
    transpose_w<<<dim3(32, 32), 256, 0, stream>>>(Wv, WTv);
    transpose_w<<<dim3(32, 32), 256, 0, stream>>>(Wo, WTo);

    proj_gemm<<<dim3(64, 8, 3), 256, 0, stream>>>(Xq, Xk, Xv, WTq, WTk, WTv,
                                                  bq, bk, bv, QW, KW, VTb);
    attn_kernel<<<dim3(64, 4), 512, 0, stream>>>(QW, KW, VTb, vmask, Ob);
    out_gemm<<<dim3(64, 8), 256, 0, stream>>>(Ob, WTo, bo, qmask, out);
}